// Round 2
// baseline (805.558 us; speedup 1.0000x reference)
//
#include <hip/hip_runtime.h>
#include <math.h>

// GAT predictor: B=64, N=512, ATOM=34, GAT=128, HID=256, 3 layers + out layer.
// fp32, register-tiled. ws layout (floats):
//   Wh    [64*512*128]           off 0
//   src   [64*512]               off 4194304
//   dst   [64*512]               off 4227072
//   multi [64*512*384]           off 4259840   (x aliases multi once multi is dead)
// total ~64.3 MB (same as round-0, known to fit).

#define ALPHA 0.2f
#define NEG_INF -9e15f

// C[row, col0+nc*4..] = act(A[row,:K] @ W[:, col0..]), 64-row x 128-col tile.
// Thread = (mr = t>>5: 8 rows, nc = t&31: 4 cols). Optional fused src/dst epilogue.
__global__ __launch_bounds__(256) void gemm_rt(
    const float* __restrict__ A, const float* __restrict__ W,
    const float* __restrict__ bias, float* __restrict__ C,
    const float* __restrict__ avec, float* __restrict__ src, float* __restrict__ dst,
    const int K, const int Wst, const int ostride, const int mode)
{
  __shared__ float AsT[32][76];   // [kk][row], stride 76 floats = 304 B (16B-aligned rows)
  __shared__ float Ws[32][128];
  const int t = threadIdx.x;
  const long row0 = (long)blockIdx.x * 64;
  const int col0 = blockIdx.y * 128;
  const int mr = t >> 5, nc = t & 31;
  float acc[8][4];
#pragma unroll
  for (int r = 0; r < 8; r++)
#pragma unroll
    for (int c = 0; c < 4; c++) acc[r][c] = 0.f;

  for (int k0 = 0; k0 < K; k0 += 32) {
    {
      int idx = t;
#pragma unroll
      for (int i = 0; i < 8; i++, idx += 256) {   // 64x32 A elements
        int r = idx >> 5, kk = idx & 31;
        float v = 0.f;
        if (k0 + kk < K) v = A[(row0 + r) * K + k0 + kk];
        AsT[kk][r] = v;
      }
    }
    {
      int idx = t;
#pragma unroll
      for (int i = 0; i < 16; i++, idx += 256) {  // 32x128 W elements
        int kk = idx >> 7, g = idx & 127;
        float v = 0.f;
        if (k0 + kk < K) v = W[(long)(k0 + kk) * Wst + col0 + g];
        Ws[kk][g] = v;
      }
    }
    __syncthreads();
#pragma unroll 4
    for (int kk = 0; kk < 32; kk++) {
      const float4 wv = *(const float4*)&Ws[kk][nc * 4];
      const float4 a0 = *(const float4*)&AsT[kk][mr * 8];      // broadcast within wave
      const float4 a1 = *(const float4*)&AsT[kk][mr * 8 + 4];
#define GFMA(r, av) \
      acc[r][0] += (av) * wv.x; acc[r][1] += (av) * wv.y; \
      acc[r][2] += (av) * wv.z; acc[r][3] += (av) * wv.w;
      GFMA(0, a0.x) GFMA(1, a0.y) GFMA(2, a0.z) GFMA(3, a0.w)
      GFMA(4, a1.x) GFMA(5, a1.y) GFMA(6, a1.z) GFMA(7, a1.w)
#undef GFMA
    }
    __syncthreads();
  }

  // store C tile
#pragma unroll
  for (int r = 0; r < 8; r++) {
    float v0 = acc[r][0], v1 = acc[r][1], v2 = acc[r][2], v3 = acc[r][3];
    if (mode == 1) {
      const float* bp = bias + col0 + nc * 4;
      v0 += bp[0]; v1 += bp[1]; v2 += bp[2]; v3 += bp[3];
      v0 = v0 > 0.f ? v0 : ALPHA * v0; v1 = v1 > 0.f ? v1 : ALPHA * v1;
      v2 = v2 > 0.f ? v2 : ALPHA * v2; v3 = v3 > 0.f ? v3 : ALPHA * v3;
    }
    *(float4*)&C[(row0 + mr * 8 + r) * (long)ostride + col0 + nc * 4] =
        make_float4(v0, v1, v2, v3);
  }

  // fused src/dst: src[row] = Wh[row,:] . avec[0:128], dst = . avec[128:256]
  if (avec) {
    float a1v[4], a2v[4];
#pragma unroll
    for (int c = 0; c < 4; c++) { a1v[c] = avec[nc * 4 + c]; a2v[c] = avec[128 + nc * 4 + c]; }
#pragma unroll
    for (int r = 0; r < 8; r++) {
      float s = acc[r][0] * a1v[0] + acc[r][1] * a1v[1] + acc[r][2] * a1v[2] + acc[r][3] * a1v[3];
      float d = acc[r][0] * a2v[0] + acc[r][1] * a2v[1] + acc[r][2] * a2v[2] + acc[r][3] * a2v[3];
#pragma unroll
      for (int w = 1; w < 32; w <<= 1) {
        s += __shfl_xor(s, w, 64);
        d += __shfl_xor(d, w, 64);
      }
      if (nc == 0) {
        src[row0 + mr * 8 + r] = s;
        dst[row0 + mr * 8 + r] = d;
      }
    }
  }
}

// Fused attention: 32 i-rows x all 512 j per block.
// out[i,c] = elu( softmax_j(mask(leaky(src_i+dst_j))) @ Wh[:,c] )
__global__ __launch_bounds__(256) void attn32_kernel(
    const float* __restrict__ Wh,   // [B*512,128]
    const int*   __restrict__ adj,  // [B,512,512]
    const float* __restrict__ src, const float* __restrict__ dst,
    float* __restrict__ out, const int ostride, const int ocoff)
{
  __shared__ float pT[512][36];    // [j][row(32) pad 36], 73.7 KB; rows 16B-aligned
  __shared__ float sinv[32];
  const int t = threadIdx.x;
  const long base = (long)blockIdx.y * 512;
  const int i0 = blockIdx.x * 32;

  // phase 1: 8 threads per row, 64 j's each (as 16 x int4/float4)
  {
    const int r = t >> 3, l8 = t & 7;
    const long i = base + i0 + r;
    const float si = src[i];
    const int* __restrict__ arow = adj + i * 512;
    const float* __restrict__ drow = dst + base;
    float m = -INFINITY;
#pragma unroll
    for (int jj = 0; jj < 16; jj++) {
      const int j = jj * 32 + l8 * 4;
      const int4 av = *(const int4*)&arow[j];
      const float4 dv = *(const float4*)&drow[j];
      float e0 = si + dv.x, e1 = si + dv.y, e2 = si + dv.z, e3 = si + dv.w;
      e0 = e0 > 0.f ? e0 : ALPHA * e0; e1 = e1 > 0.f ? e1 : ALPHA * e1;
      e2 = e2 > 0.f ? e2 : ALPHA * e2; e3 = e3 > 0.f ? e3 : ALPHA * e3;
      e0 = av.x > 0 ? e0 : NEG_INF; e1 = av.y > 0 ? e1 : NEG_INF;
      e2 = av.z > 0 ? e2 : NEG_INF; e3 = av.w > 0 ? e3 : NEG_INF;
      pT[j + 0][r] = e0; pT[j + 1][r] = e1; pT[j + 2][r] = e2; pT[j + 3][r] = e3;
      m = fmaxf(m, fmaxf(fmaxf(e0, e1), fmaxf(e2, e3)));
    }
#pragma unroll
    for (int w = 1; w < 8; w <<= 1) m = fmaxf(m, __shfl_xor(m, w, 64));
    float sum = 0.f;
#pragma unroll
    for (int jj = 0; jj < 16; jj++) {
      const int j = jj * 32 + l8 * 4;
      float p0 = __expf(pT[j + 0][r] - m); float p1 = __expf(pT[j + 1][r] - m);
      float p2 = __expf(pT[j + 2][r] - m); float p3 = __expf(pT[j + 3][r] - m);
      pT[j + 0][r] = p0; pT[j + 1][r] = p1; pT[j + 2][r] = p2; pT[j + 3][r] = p3;
      sum += p0 + p1 + p2 + p3;
    }
#pragma unroll
    for (int w = 1; w < 8; w <<= 1) sum += __shfl_xor(sum, w, 64);
    if (l8 == 0) sinv[r] = 1.f / sum;
  }
  __syncthreads();

  // phase 2: out[mr*8+r, nc*2+c] = sum_j pT[j][mr*8+r] * Wh[base+j][nc*2+c]
  const int mr = t >> 6;   // wave id -> 8-row group (broadcast LDS reads)
  const int nc = t & 63;   // 2-col group
  float acc[8][2];
#pragma unroll
  for (int r = 0; r < 8; r++) { acc[r][0] = 0.f; acc[r][1] = 0.f; }
  const float* __restrict__ whp = Wh + base * 128 + nc * 2;
  for (int j = 0; j < 512; j += 4) {
#define AJ(jo) { \
    const float2 w = *(const float2*)&whp[(j + jo) * 128]; \
    const float4 pa = *(const float4*)&pT[j + jo][mr * 8]; \
    const float4 pb = *(const float4*)&pT[j + jo][mr * 8 + 4]; \
    acc[0][0] += pa.x * w.x; acc[0][1] += pa.x * w.y; \
    acc[1][0] += pa.y * w.x; acc[1][1] += pa.y * w.y; \
    acc[2][0] += pa.z * w.x; acc[2][1] += pa.z * w.y; \
    acc[3][0] += pa.w * w.x; acc[3][1] += pa.w * w.y; \
    acc[4][0] += pb.x * w.x; acc[4][1] += pb.x * w.y; \
    acc[5][0] += pb.y * w.x; acc[5][1] += pb.y * w.y; \
    acc[6][0] += pb.z * w.x; acc[6][1] += pb.z * w.y; \
    acc[7][0] += pb.w * w.x; acc[7][1] += pb.w * w.y; }
    AJ(0) AJ(1) AJ(2) AJ(3)
#undef AJ
  }

#pragma unroll
  for (int r = 0; r < 8; r++) {
    const float inv = sinv[mr * 8 + r];
    float v0 = acc[r][0] * inv, v1 = acc[r][1] * inv;
    v0 = v0 > 0.f ? v0 : expm1f(v0);   // elu
    v1 = v1 > 0.f ? v1 : expm1f(v1);
    *(float2*)&out[(base + i0 + mr * 8 + r) * (long)ostride + ocoff + nc * 2] =
        make_float2(v0, v1);
  }
}

extern "C" void kernel_launch(void* const* d_in, const int* in_sizes, int n_in,
                              void* d_out, int out_size, void* d_ws, size_t ws_size,
                              hipStream_t stream) {
  const float* compound = (const float*)d_in[0];   // [64,512,34]
  const int*   adj      = (const int*)d_in[1];     // [64,512,512]
  const float* W_stack  = (const float*)d_in[2];   // [3,34,128]
  const float* a_stack  = (const float*)d_in[3];   // [3,256,1]
  const float* W_out    = (const float*)d_in[4];   // [384,128]
  const float* a_out    = (const float*)d_in[5];   // [256,1]
  const float* Wc       = (const float*)d_in[6];   // [128,256]
  const float* bc       = (const float*)d_in[7];   // [256]
  float* out = (float*)d_out;                      // [64,512,256]

  float* f     = (float*)d_ws;
  float* Wh    = f;                       // 4,194,304 floats
  float* src   = f + 4194304;             // 32,768
  float* dstv  = f + 4194304 + 32768;     // 32,768
  float* multi = f + 4194304 + 65536;     // 12,582,912
  float* x     = multi;                   // aliases multi (dead by then)

  for (int l = 0; l < 3; l++) {
    gemm_rt<<<dim3(512, 1), 256, 0, stream>>>(
        compound, W_stack + (long)l * 34 * 128, nullptr, Wh,
        a_stack + (long)l * 256, src, dstv, 34, 128, 128, 0);
    attn32_kernel<<<dim3(16, 64), 256, 0, stream>>>(Wh, adj, src, dstv, multi, 384, l * 128);
  }
  gemm_rt<<<dim3(512, 1), 256, 0, stream>>>(
      multi, W_out, nullptr, Wh, a_out, src, dstv, 384, 128, 128, 0);
  attn32_kernel<<<dim3(16, 64), 256, 0, stream>>>(Wh, adj, src, dstv, x, 128, 0);
  gemm_rt<<<dim3(512, 2), 256, 0, stream>>>(
      x, Wc, bc, out, nullptr, nullptr, nullptr, 128, 256, 256, 1);
}

// Round 3
// 620.967 us; speedup vs baseline: 1.2973x; 1.2973x over previous
//
#include <hip/hip_runtime.h>
#include <math.h>

// GAT predictor: B=64, N=512, ATOM=34, GAT=128, HID=256, 3 layers + out layer.
// fp32. Empirical MI355X law from rounds 0-2: keep >=4 blocks/CU (grid>=1024,
// LDS<=41KB) or fall off a ~6x latency cliff. ws layout (floats):
//   Wh [64*512*128] | src [32768] | dst [32768] | multi [64*512*384] (x aliases multi)

#define ALPHA 0.2f
#define NEG_INF -9e15f

// ---- K1: Wh = compound[32768,34] @ W[34,128], fused src/dst. grid 1024. ----
__global__ __launch_bounds__(256) void wh_small(
    const float* __restrict__ A, const float* __restrict__ W,
    const float* __restrict__ avec, float* __restrict__ Wh,
    float* __restrict__ src, float* __restrict__ dst)
{
  __shared__ float AsT[34][36];   // [k][row], 16B-aligned rows (144 B)
  __shared__ float Ws[34][128];
  const int t = threadIdx.x;
  const long row0 = (long)blockIdx.x * 32;
  const int cg = t & 31, rg = t >> 5;    // 4 cols x 4 rows per thread
  {
    const int r = t >> 3, l8 = t & 7;    // 32 rows x 8 loaders
#pragma unroll
    for (int q = 0; q < 5; q++) {
      int k = l8 + q * 8;
      if (k < 34) AsT[k][r] = A[(row0 + r) * 34 + k];
    }
  }
  {
    int idx = t;
#pragma unroll
    for (int i = 0; i < 17; i++, idx += 256)   // 34*128 = 4352 exact
      Ws[idx >> 7][idx & 127] = W[idx];
  }
  __syncthreads();

  float acc[4][4];
#pragma unroll
  for (int r = 0; r < 4; r++)
#pragma unroll
    for (int c = 0; c < 4; c++) acc[r][c] = 0.f;

#pragma unroll 2
  for (int k = 0; k < 34; k++) {
    const float4 wv = *(const float4*)&Ws[k][cg * 4];
    const float4 av = *(const float4*)&AsT[k][rg * 4];
#define GFMA(r, a) \
    acc[r][0] += (a) * wv.x; acc[r][1] += (a) * wv.y; \
    acc[r][2] += (a) * wv.z; acc[r][3] += (a) * wv.w;
    GFMA(0, av.x) GFMA(1, av.y) GFMA(2, av.z) GFMA(3, av.w)
#undef GFMA
  }

#pragma unroll
  for (int r = 0; r < 4; r++)
    *(float4*)&Wh[(row0 + rg * 4 + r) * 128 + cg * 4] =
        make_float4(acc[r][0], acc[r][1], acc[r][2], acc[r][3]);

  // fused src/dst: reduce over 128 cols = 32 lanes x 4
  const float4 a1 = *(const float4*)&avec[cg * 4];
  const float4 a2 = *(const float4*)&avec[128 + cg * 4];
#pragma unroll
  for (int r = 0; r < 4; r++) {
    float s = acc[r][0]*a1.x + acc[r][1]*a1.y + acc[r][2]*a1.z + acc[r][3]*a1.w;
    float d = acc[r][0]*a2.x + acc[r][1]*a2.y + acc[r][2]*a2.z + acc[r][3]*a2.w;
#pragma unroll
    for (int w = 1; w < 32; w <<= 1) {
      s += __shfl_xor(s, w, 64);
      d += __shfl_xor(d, w, 64);
    }
    if (cg == 0) {
      src[row0 + rg * 4 + r] = s;
      dst[row0 + rg * 4 + r] = d;
    }
  }
}

// ---- K3/K4: C = A[32768,K] @ W[K,G], 32x128 tile, K-chunks of 32. ----
// mode 0: plain store (+optional fused src/dst).  mode 1: +bias +leaky_relu.
__global__ __launch_bounds__(256) void gemm_big(
    const float* __restrict__ A, const float* __restrict__ W,
    const float* __restrict__ bias, float* __restrict__ C,
    const float* __restrict__ avec, float* __restrict__ src, float* __restrict__ dst,
    const int K, const int Wst, const int ostride, const int mode)
{
  __shared__ float AsT[32][36];
  __shared__ float Ws[32][128];
  const int t = threadIdx.x;
  const long row0 = (long)blockIdx.x * 32;
  const int col0 = blockIdx.y * 128;
  const int cg = t & 31, rg = t >> 5;
  float acc[4][4];
#pragma unroll
  for (int r = 0; r < 4; r++)
#pragma unroll
    for (int c = 0; c < 4; c++) acc[r][c] = 0.f;

  for (int k0 = 0; k0 < K; k0 += 32) {
    {
      int idx = t;
#pragma unroll
      for (int i = 0; i < 4; i++, idx += 256) {  // 32x32
        int r = idx >> 5, kk = idx & 31;
        AsT[kk][r] = A[(row0 + r) * (long)K + k0 + kk];
      }
    }
    {
      int idx = t;
#pragma unroll
      for (int i = 0; i < 16; i++, idx += 256) { // 32x128
        int kk = idx >> 7, g = idx & 127;
        Ws[kk][g] = W[(long)(k0 + kk) * Wst + col0 + g];
      }
    }
    __syncthreads();
#pragma unroll 4
    for (int kk = 0; kk < 32; kk++) {
      const float4 wv = *(const float4*)&Ws[kk][cg * 4];
      const float4 av = *(const float4*)&AsT[kk][rg * 4];
#define GFMA(r, a) \
      acc[r][0] += (a) * wv.x; acc[r][1] += (a) * wv.y; \
      acc[r][2] += (a) * wv.z; acc[r][3] += (a) * wv.w;
      GFMA(0, av.x) GFMA(1, av.y) GFMA(2, av.z) GFMA(3, av.w)
#undef GFMA
    }
    __syncthreads();
  }

#pragma unroll
  for (int r = 0; r < 4; r++) {
    float v0 = acc[r][0], v1 = acc[r][1], v2 = acc[r][2], v3 = acc[r][3];
    if (mode == 1) {
      const float4 bv = *(const float4*)&bias[col0 + cg * 4];
      v0 += bv.x; v1 += bv.y; v2 += bv.z; v3 += bv.w;
      v0 = v0 > 0.f ? v0 : ALPHA * v0; v1 = v1 > 0.f ? v1 : ALPHA * v1;
      v2 = v2 > 0.f ? v2 : ALPHA * v2; v3 = v3 > 0.f ? v3 : ALPHA * v3;
    }
    *(float4*)&C[(row0 + rg * 4 + r) * (long)ostride + col0 + cg * 4] =
        make_float4(v0, v1, v2, v3);
  }

  if (avec) {
    const float4 a1 = *(const float4*)&avec[cg * 4];
    const float4 a2 = *(const float4*)&avec[128 + cg * 4];
#pragma unroll
    for (int r = 0; r < 4; r++) {
      float s = acc[r][0]*a1.x + acc[r][1]*a1.y + acc[r][2]*a1.z + acc[r][3]*a1.w;
      float d = acc[r][0]*a2.x + acc[r][1]*a2.y + acc[r][2]*a2.z + acc[r][3]*a2.w;
#pragma unroll
      for (int w = 1; w < 32; w <<= 1) {
        s += __shfl_xor(s, w, 64);
        d += __shfl_xor(d, w, 64);
      }
      if (cg == 0) {
        src[row0 + rg * 4 + r] = s;
        dst[row0 + rg * 4 + r] = d;
      }
    }
  }
}

// ---- K2: fused attention, 16 i-rows x 512 j per block (round-0 proven shape,
// 41 KB LDS -> 3-4 blocks/CU), int4 adj loads. grid (32,64) = 2048 blocks. ----
__global__ __launch_bounds__(256) void attn16(
    const float* __restrict__ Wh,   // [B*512,128]
    const int*   __restrict__ adj,  // [B,512,512]
    const float* __restrict__ src, const float* __restrict__ dst,
    float* __restrict__ out, const int ostride, const int ocoff)
{
  __shared__ float pT[512][20];    // [j][row], rows 80 B (16B-aligned)
  __shared__ float sinv[16];
  const int t = threadIdx.x;
  const long base = (long)blockIdx.y * 512;
  const int i0 = blockIdx.x * 16;

  // phase 1: 16 threads/row, 32 j's each as 8x(int4,float4)
  {
    const int r = t >> 4, l16 = t & 15;
    const long i = base + i0 + r;
    const float si = src[i];
    const int* __restrict__ arow = adj + i * 512;
    const float* __restrict__ drow = dst + base;
    float4 sv[8];
    float m = -INFINITY;
#pragma unroll
    for (int jj = 0; jj < 8; jj++) {
      const int j = jj * 64 + l16 * 4;
      const int4 av = *(const int4*)&arow[j];
      const float4 dv = *(const float4*)&drow[j];
      float e0 = si + dv.x, e1 = si + dv.y, e2 = si + dv.z, e3 = si + dv.w;
      e0 = e0 > 0.f ? e0 : ALPHA * e0; e1 = e1 > 0.f ? e1 : ALPHA * e1;
      e2 = e2 > 0.f ? e2 : ALPHA * e2; e3 = e3 > 0.f ? e3 : ALPHA * e3;
      e0 = av.x > 0 ? e0 : NEG_INF; e1 = av.y > 0 ? e1 : NEG_INF;
      e2 = av.z > 0 ? e2 : NEG_INF; e3 = av.w > 0 ? e3 : NEG_INF;
      sv[jj] = make_float4(e0, e1, e2, e3);
      m = fmaxf(m, fmaxf(fmaxf(e0, e1), fmaxf(e2, e3)));
    }
#pragma unroll
    for (int w = 1; w < 16; w <<= 1) m = fmaxf(m, __shfl_xor(m, w, 16));
    float sum = 0.f;
#pragma unroll
    for (int jj = 0; jj < 8; jj++) {
      const int j = jj * 64 + l16 * 4;
      float p0 = __expf(sv[jj].x - m), p1 = __expf(sv[jj].y - m);
      float p2 = __expf(sv[jj].z - m), p3 = __expf(sv[jj].w - m);
      pT[j + 0][r] = p0; pT[j + 1][r] = p1; pT[j + 2][r] = p2; pT[j + 3][r] = p3;
      sum += p0 + p1 + p2 + p3;
    }
#pragma unroll
    for (int w = 1; w < 16; w <<= 1) sum += __shfl_xor(sum, w, 16);
    if (l16 == 0) sinv[r] = 1.f / sum;
  }
  __syncthreads();

  // phase 2: out[r,c] = sum_j pT[j][r] * Wh[j,c]; thread = (c, j-half)
  const int c = t & 127, jh = t >> 7;
  float acc[16];
#pragma unroll
  for (int r = 0; r < 16; r++) acc[r] = 0.f;
  const float* __restrict__ whp = Wh + (base + jh * 256) * 128 + c;
  const float (* __restrict__ pTh)[20] = (const float (*)[20])&pT[jh * 256];
#pragma unroll 4
  for (int j = 0; j < 256; j++) {
    const float w = whp[j * 128];
    const float4 p0 = *(const float4*)&pTh[j][0];
    const float4 p1 = *(const float4*)&pTh[j][4];
    const float4 p2 = *(const float4*)&pTh[j][8];
    const float4 p3 = *(const float4*)&pTh[j][12];
    acc[0]  += p0.x * w; acc[1]  += p0.y * w; acc[2]  += p0.z * w; acc[3]  += p0.w * w;
    acc[4]  += p1.x * w; acc[5]  += p1.y * w; acc[6]  += p1.z * w; acc[7]  += p1.w * w;
    acc[8]  += p2.x * w; acc[9]  += p2.y * w; acc[10] += p2.z * w; acc[11] += p2.w * w;
    acc[12] += p3.x * w; acc[13] += p3.y * w; acc[14] += p3.z * w; acc[15] += p3.w * w;
  }
  __syncthreads();          // pT reads done; reuse as combine scratch
  if (jh == 1) {
#pragma unroll
    for (int r = 0; r < 16; r++) pT[c][r] = acc[r];
  }
  __syncthreads();
  if (jh == 0) {
#pragma unroll
    for (int r = 0; r < 16; r++) {
      float v = (acc[r] + pT[c][r]) * sinv[r];
      v = v > 0.f ? v : expm1f(v);   // elu
      out[(base + i0 + r) * (long)ostride + ocoff + c] = v;
    }
  }
}

extern "C" void kernel_launch(void* const* d_in, const int* in_sizes, int n_in,
                              void* d_out, int out_size, void* d_ws, size_t ws_size,
                              hipStream_t stream) {
  const float* compound = (const float*)d_in[0];   // [64,512,34]
  const int*   adj      = (const int*)d_in[1];     // [64,512,512]
  const float* W_stack  = (const float*)d_in[2];   // [3,34,128]
  const float* a_stack  = (const float*)d_in[3];   // [3,256,1]
  const float* W_out    = (const float*)d_in[4];   // [384,128]
  const float* a_out    = (const float*)d_in[5];   // [256,1]
  const float* Wc       = (const float*)d_in[6];   // [128,256]
  const float* bc       = (const float*)d_in[7];   // [256]
  float* out = (float*)d_out;                      // [64,512,256]

  float* f     = (float*)d_ws;
  float* Wh    = f;                       // 4,194,304 floats
  float* src   = f + 4194304;             // 32,768
  float* dstv  = f + 4194304 + 32768;     // 32,768
  float* multi = f + 4194304 + 65536;     // 12,582,912
  float* x     = multi;                   // aliases multi (dead by then)

  for (int l = 0; l < 3; l++) {
    wh_small<<<1024, 256, 0, stream>>>(
        compound, W_stack + (long)l * 34 * 128, a_stack + (long)l * 256,
        Wh, src, dstv);
    attn16<<<dim3(32, 64), 256, 0, stream>>>(Wh, adj, src, dstv, multi, 384, l * 128);
  }
  gemm_big<<<dim3(1024, 1), 256, 0, stream>>>(
      multi, W_out, nullptr, Wh, a_out, src, dstv, 384, 128, 128, 0);
  attn16<<<dim3(32, 64), 256, 0, stream>>>(Wh, adj, src, dstv, x, 128, 0);
  gemm_big<<<dim3(1024, 2), 256, 0, stream>>>(
      x, Wc, bc, out, nullptr, nullptr, nullptr, 128, 256, 256, 1);
}

// Round 4
// 503.649 us; speedup vs baseline: 1.5994x; 1.2329x over previous
//
#include <hip/hip_runtime.h>
#include <math.h>

// GAT predictor: B=64, N=512, ATOM=34, GAT=128, HID=256, 3 layers + out.
// Round-4: attention aggregation on MFMA (split-bf16 hi/lo, 3-term compensated).
// Producer GEMMs emit WhT[b][c][j] as bf16 hi+lo (B-fragment layout) + src/dst.
// ws (floats): WhT_hi+WhT_lo [4,194,304] | src [32768] | dst [32768] | multi [12,582,912]

#define ALPHA 0.2f
#define NEG_INF -9e15f

typedef __attribute__((ext_vector_type(8))) short s16x8;   // 8 bf16 (4 VGPRs)
typedef __attribute__((ext_vector_type(4))) float f32x4;

__device__ __forceinline__ ushort bf16_rne(float f) {
  union { float f; unsigned u; } v; v.f = f;
  unsigned r = v.u + 0x7FFFu + ((v.u >> 16) & 1u);
  return (ushort)(r >> 16);
}
__device__ __forceinline__ float bf16_tof(ushort h) {
  union { unsigned u; float f; } v; v.u = ((unsigned)h) << 16;
  return v.f;
}
__device__ __forceinline__ void split_store4(
    ushort* __restrict__ ph, ushort* __restrict__ pl,
    float v0, float v1, float v2, float v3) {
  ushort h0 = bf16_rne(v0), h1 = bf16_rne(v1), h2 = bf16_rne(v2), h3 = bf16_rne(v3);
  *(ushort4*)ph = make_ushort4(h0, h1, h2, h3);
  *(ushort4*)pl = make_ushort4(bf16_rne(v0 - bf16_tof(h0)), bf16_rne(v1 - bf16_tof(h1)),
                               bf16_rne(v2 - bf16_tof(h2)), bf16_rne(v3 - bf16_tof(h3)));
}

// ---- K1: Wh = compound[32768,34]@W[34,128] -> WhT bf16 hi/lo + src/dst. ----
__global__ __launch_bounds__(256) void wh_small(
    const float* __restrict__ A, const float* __restrict__ W,
    const float* __restrict__ avec,
    ushort* __restrict__ whtH, ushort* __restrict__ whtL,
    float* __restrict__ src, float* __restrict__ dst)
{
  __shared__ float AsT[34][36];
  __shared__ float Ws[34][128];
  const int t = threadIdx.x;
  const long row0 = (long)blockIdx.x * 32;
  const int cg = t & 31, rg = t >> 5;
  {
    const int r = t >> 3, l8 = t & 7;
#pragma unroll
    for (int q = 0; q < 5; q++) {
      int k = l8 + q * 8;
      if (k < 34) AsT[k][r] = A[(row0 + r) * 34 + k];
    }
  }
  {
    int idx = t;
#pragma unroll
    for (int i = 0; i < 17; i++, idx += 256)
      Ws[idx >> 7][idx & 127] = W[idx];
  }
  __syncthreads();

  float acc[4][4];
#pragma unroll
  for (int r = 0; r < 4; r++)
#pragma unroll
    for (int c = 0; c < 4; c++) acc[r][c] = 0.f;
#pragma unroll 2
  for (int k = 0; k < 34; k++) {
    const float4 wv = *(const float4*)&Ws[k][cg * 4];
    const float4 av = *(const float4*)&AsT[k][rg * 4];
#define GFMA(r, a) \
    acc[r][0] += (a) * wv.x; acc[r][1] += (a) * wv.y; \
    acc[r][2] += (a) * wv.z; acc[r][3] += (a) * wv.w;
    GFMA(0, av.x) GFMA(1, av.y) GFMA(2, av.z) GFMA(3, av.w)
#undef GFMA
  }

  // transposed bf16 hi/lo store: WhT[b][c][j], 4 consecutive j per ushort4
  {
    const long tb = (row0 >> 9) * 65536;           // batch * 128 * 512
    const int jloc = (int)(row0 & 511) + rg * 4;
#pragma unroll
    for (int cc = 0; cc < 4; cc++) {
      const long o = tb + (long)(cg * 4 + cc) * 512 + jloc;
      split_store4(&whtH[o], &whtL[o], acc[0][cc], acc[1][cc], acc[2][cc], acc[3][cc]);
    }
  }

  const float4 a1 = *(const float4*)&avec[cg * 4];
  const float4 a2 = *(const float4*)&avec[128 + cg * 4];
#pragma unroll
  for (int r = 0; r < 4; r++) {
    float s = acc[r][0]*a1.x + acc[r][1]*a1.y + acc[r][2]*a1.z + acc[r][3]*a1.w;
    float d = acc[r][0]*a2.x + acc[r][1]*a2.y + acc[r][2]*a2.z + acc[r][3]*a2.w;
#pragma unroll
    for (int w = 1; w < 32; w <<= 1) {
      s += __shfl_xor(s, w, 64);
      d += __shfl_xor(d, w, 64);
    }
    if (cg == 0) {
      src[row0 + rg * 4 + r] = s;
      dst[row0 + rg * 4 + r] = d;
    }
  }
}

// ---- K3/K4: C = A[32768,K]@W[K,G]. whtH!=null: WhT bf16 hi/lo + src/dst out.
//      whtH==null: fp32 C store, mode 1 adds bias+leaky. ----
__global__ __launch_bounds__(256) void gemm_big(
    const float* __restrict__ A, const float* __restrict__ W,
    const float* __restrict__ bias, float* __restrict__ C,
    const float* __restrict__ avec,
    ushort* __restrict__ whtH, ushort* __restrict__ whtL,
    float* __restrict__ src, float* __restrict__ dst,
    const int K, const int Wst, const int ostride, const int mode)
{
  __shared__ float AsT[32][36];
  __shared__ float Ws[32][128];
  const int t = threadIdx.x;
  const long row0 = (long)blockIdx.x * 32;
  const int col0 = blockIdx.y * 128;
  const int cg = t & 31, rg = t >> 5;
  float acc[4][4];
#pragma unroll
  for (int r = 0; r < 4; r++)
#pragma unroll
    for (int c = 0; c < 4; c++) acc[r][c] = 0.f;

  for (int k0 = 0; k0 < K; k0 += 32) {
    {
      int idx = t;
#pragma unroll
      for (int i = 0; i < 4; i++, idx += 256) {
        int r = idx >> 5, kk = idx & 31;
        AsT[kk][r] = A[(row0 + r) * (long)K + k0 + kk];
      }
    }
    {
      int idx = t;
#pragma unroll
      for (int i = 0; i < 16; i++, idx += 256) {
        int kk = idx >> 7, g = idx & 127;
        Ws[kk][g] = W[(long)(k0 + kk) * Wst + col0 + g];
      }
    }
    __syncthreads();
#pragma unroll 4
    for (int kk = 0; kk < 32; kk++) {
      const float4 wv = *(const float4*)&Ws[kk][cg * 4];
      const float4 av = *(const float4*)&AsT[kk][rg * 4];
#define GFMA(r, a) \
      acc[r][0] += (a) * wv.x; acc[r][1] += (a) * wv.y; \
      acc[r][2] += (a) * wv.z; acc[r][3] += (a) * wv.w;
      GFMA(0, av.x) GFMA(1, av.y) GFMA(2, av.z) GFMA(3, av.w)
#undef GFMA
    }
    __syncthreads();
  }

  if (whtH) {
    const long tb = (row0 >> 9) * 65536;
    const int jloc = (int)(row0 & 511) + rg * 4;
#pragma unroll
    for (int cc = 0; cc < 4; cc++) {
      const long o = tb + (long)(cg * 4 + cc) * 512 + jloc;
      split_store4(&whtH[o], &whtL[o], acc[0][cc], acc[1][cc], acc[2][cc], acc[3][cc]);
    }
  } else {
#pragma unroll
    for (int r = 0; r < 4; r++) {
      float v0 = acc[r][0], v1 = acc[r][1], v2 = acc[r][2], v3 = acc[r][3];
      if (mode == 1) {
        const float4 bv = *(const float4*)&bias[col0 + cg * 4];
        v0 += bv.x; v1 += bv.y; v2 += bv.z; v3 += bv.w;
        v0 = v0 > 0.f ? v0 : ALPHA * v0; v1 = v1 > 0.f ? v1 : ALPHA * v1;
        v2 = v2 > 0.f ? v2 : ALPHA * v2; v3 = v3 > 0.f ? v3 : ALPHA * v3;
      }
      *(float4*)&C[(row0 + rg * 4 + r) * (long)ostride + col0 + cg * 4] =
          make_float4(v0, v1, v2, v3);
    }
  }

  if (avec) {
    const float4 a1 = *(const float4*)&avec[cg * 4];
    const float4 a2 = *(const float4*)&avec[128 + cg * 4];
#pragma unroll
    for (int r = 0; r < 4; r++) {
      float s = acc[r][0]*a1.x + acc[r][1]*a1.y + acc[r][2]*a1.z + acc[r][3]*a1.w;
      float d = acc[r][0]*a2.x + acc[r][1]*a2.y + acc[r][2]*a2.z + acc[r][3]*a2.w;
#pragma unroll
      for (int w = 1; w < 32; w <<= 1) {
        s += __shfl_xor(s, w, 64);
        d += __shfl_xor(d, w, 64);
      }
      if (cg == 0) {
        src[row0 + rg * 4 + r] = s;
        dst[row0 + rg * 4 + r] = d;
      }
    }
  }
}

// ---- K2: MFMA attention. 16 i-rows x 512 j per block, 4 waves.
// out = elu( (P@Wh) * sinv ), P@Wh via 3-term split-bf16 16x16x32 MFMA. ----
__global__ __launch_bounds__(256) void attn_mfma(
    const ushort* __restrict__ whtH, const ushort* __restrict__ whtL,
    const int*   __restrict__ adj,
    const float* __restrict__ src, const float* __restrict__ dst,
    float* __restrict__ out, const int ostride, const int ocoff)
{
  __shared__ ushort pH[16][520];   // [m][k], row stride 1040 B (16B-aligned, 2-way banks)
  __shared__ ushort pL[16][520];
  __shared__ float sinv[16];
  const int t = threadIdx.x;
  const long base = (long)blockIdx.y * 512;
  const int i0 = blockIdx.x * 16;

  // phase 1: scores -> softmax numerators p (bf16 hi/lo into LDS), 1/sum
  {
    const int r = t >> 4, l16 = t & 15;
    const long i = base + i0 + r;
    const float si = src[i];
    const int* __restrict__ arow = adj + i * 512;
    const float* __restrict__ drow = dst + base;
    float4 sv[8];
    float m = -INFINITY;
#pragma unroll
    for (int jj = 0; jj < 8; jj++) {
      const int j = jj * 64 + l16 * 4;
      const int4 av = *(const int4*)&arow[j];
      const float4 dv = *(const float4*)&drow[j];
      float e0 = si + dv.x, e1 = si + dv.y, e2 = si + dv.z, e3 = si + dv.w;
      e0 = e0 > 0.f ? e0 : ALPHA * e0; e1 = e1 > 0.f ? e1 : ALPHA * e1;
      e2 = e2 > 0.f ? e2 : ALPHA * e2; e3 = e3 > 0.f ? e3 : ALPHA * e3;
      e0 = av.x > 0 ? e0 : NEG_INF; e1 = av.y > 0 ? e1 : NEG_INF;
      e2 = av.z > 0 ? e2 : NEG_INF; e3 = av.w > 0 ? e3 : NEG_INF;
      sv[jj] = make_float4(e0, e1, e2, e3);
      m = fmaxf(m, fmaxf(fmaxf(e0, e1), fmaxf(e2, e3)));
    }
#pragma unroll
    for (int w = 1; w < 16; w <<= 1) m = fmaxf(m, __shfl_xor(m, w, 16));
    float sum = 0.f;
#pragma unroll
    for (int jj = 0; jj < 8; jj++) {
      const int j = jj * 64 + l16 * 4;
      float p0 = __expf(sv[jj].x - m), p1 = __expf(sv[jj].y - m);
      float p2 = __expf(sv[jj].z - m), p3 = __expf(sv[jj].w - m);
      split_store4(&pH[r][j], &pL[r][j], p0, p1, p2, p3);
      sum += p0 + p1 + p2 + p3;
    }
#pragma unroll
    for (int w = 1; w < 16; w <<= 1) sum += __shfl_xor(sum, w, 16);
    if (l16 == 0) sinv[r] = 1.f / sum;
  }
  __syncthreads();

  // phase 2: wave w -> output cols [w*32, w*32+32), two 16x16 tiles, K=512
  const int wv = t >> 6, lane = t & 63;
  const int m16 = lane & 15, q = lane >> 4;
  const int n0 = wv * 32;
  const long bb = base * 128;                       // batch base in WhT (ushorts)
  const ushort* __restrict__ bH = whtH + bb + (long)(n0 + m16) * 512;
  const ushort* __restrict__ bL = whtL + bb + (long)(n0 + m16) * 512;
  f32x4 acc0 = {0.f, 0.f, 0.f, 0.f}, acc1 = {0.f, 0.f, 0.f, 0.f};
#pragma unroll 4
  for (int kb = 0; kb < 16; kb++) {
    const int k0 = kb * 32 + q * 8;
    const s16x8 aH = *(const s16x8*)&pH[m16][k0];
    const s16x8 aL = *(const s16x8*)&pL[m16][k0];
    const s16x8 b0H = *(const s16x8*)&bH[k0];
    const s16x8 b0L = *(const s16x8*)&bL[k0];
    const s16x8 b1H = *(const s16x8*)&bH[8192 + k0];  // +16 cols * 512
    const s16x8 b1L = *(const s16x8*)&bL[8192 + k0];
    acc0 = __builtin_amdgcn_mfma_f32_16x16x32_bf16(aH, b0H, acc0, 0, 0, 0);
    acc1 = __builtin_amdgcn_mfma_f32_16x16x32_bf16(aH, b1H, acc1, 0, 0, 0);
    acc0 = __builtin_amdgcn_mfma_f32_16x16x32_bf16(aH, b0L, acc0, 0, 0, 0);
    acc1 = __builtin_amdgcn_mfma_f32_16x16x32_bf16(aH, b1L, acc1, 0, 0, 0);
    acc0 = __builtin_amdgcn_mfma_f32_16x16x32_bf16(aL, b0H, acc0, 0, 0, 0);
    acc1 = __builtin_amdgcn_mfma_f32_16x16x32_bf16(aL, b1H, acc1, 0, 0, 0);
  }
  // epilogue: C/D layout col=lane&15, row=q*4+reg
#pragma unroll
  for (int reg = 0; reg < 4; reg++) {
    const int row = q * 4 + reg;
    const float inv = sinv[row];
    float v0 = acc0[reg] * inv, v1 = acc1[reg] * inv;
    v0 = v0 > 0.f ? v0 : expm1f(v0);
    v1 = v1 > 0.f ? v1 : expm1f(v1);
    float* op = out + (base + i0 + row) * (long)ostride + ocoff + n0 + m16;
    op[0] = v0; op[16] = v1;
  }
}

extern "C" void kernel_launch(void* const* d_in, const int* in_sizes, int n_in,
                              void* d_out, int out_size, void* d_ws, size_t ws_size,
                              hipStream_t stream) {
  const float* compound = (const float*)d_in[0];
  const int*   adj      = (const int*)d_in[1];
  const float* W_stack  = (const float*)d_in[2];
  const float* a_stack  = (const float*)d_in[3];
  const float* W_out    = (const float*)d_in[4];
  const float* a_out    = (const float*)d_in[5];
  const float* Wc       = (const float*)d_in[6];
  const float* bc       = (const float*)d_in[7];
  float* out = (float*)d_out;

  ushort* whtH = (ushort*)d_ws;                       // 4,194,304 ushorts (8 MB)
  ushort* whtL = whtH + 4194304;                      // 8 MB
  float* f     = (float*)d_ws;
  float* src   = f + 4194304;                         // after hi+lo (16 MB)
  float* dstv  = f + 4194304 + 32768;
  float* multi = f + 4194304 + 65536;                 // 12,582,912 floats
  float* x     = multi;

  for (int l = 0; l < 3; l++) {
    wh_small<<<1024, 256, 0, stream>>>(
        compound, W_stack + (long)l * 34 * 128, a_stack + (long)l * 256,
        whtH, whtL, src, dstv);
    attn_mfma<<<dim3(32, 64), 256, 0, stream>>>(
        whtH, whtL, adj, src, dstv, multi, 384, l * 128);
  }
  gemm_big<<<dim3(1024, 1), 256, 0, stream>>>(
      multi, W_out, nullptr, nullptr, a_out, whtH, whtL, src, dstv, 384, 128, 0, 0);
  attn_mfma<<<dim3(32, 64), 256, 0, stream>>>(
      whtH, whtL, adj, src, dstv, x, 128, 0);
  gemm_big<<<dim3(1024, 2), 256, 0, stream>>>(
      x, Wc, bc, out, nullptr, nullptr, nullptr, nullptr, nullptr, 128, 256, 256, 1);
}